// Round 1
// baseline (564.150 us; speedup 1.0000x reference)
//
#include <hip/hip_runtime.h>
#include <stdint.h>

#define S_LEN 2048
#define D_MODEL 1024
#define N_HEAD 16
#define D_HEAD 64
#define N_BATCH 2
#define M_TOK (N_BATCH * S_LEN)  // 4096

typedef unsigned short u16;
typedef __attribute__((ext_vector_type(8))) short bf16x8;
typedef __attribute__((ext_vector_type(4))) float f32x4;
typedef __attribute__((ext_vector_type(4))) unsigned short u16x4;

#define MFMA16(a, b, c) __builtin_amdgcn_mfma_f32_16x16x32_bf16((a), (b), (c), 0, 0, 0)

__device__ __forceinline__ u16 f2bf(float f) {
  unsigned int u = __float_as_uint(f);
  u = (u + 0x7FFFu + ((u >> 16) & 1u)) >> 16;
  return (u16)u;
}

__device__ __forceinline__ void gload_lds16(const u16* g, u16* l) {
  __builtin_amdgcn_global_load_lds((const __attribute__((address_space(1))) void*)g,
                                   (__attribute__((address_space(3))) void*)l, 16, 0, 0);
}

// ---------------- fp32 -> bf16 convert (batched over up to 4 arrays) ----------------
__global__ __launch_bounds__(256) void cvt_kernel(const float* __restrict__ s0, const float* __restrict__ s1,
                                                  const float* __restrict__ s2, const float* __restrict__ s3,
                                                  u16* __restrict__ d0, u16* __restrict__ d1,
                                                  u16* __restrict__ d2, u16* __restrict__ d3, int n4) {
  const float* s;
  u16* d;
  switch (blockIdx.y) {
    case 0: s = s0; d = d0; break;
    case 1: s = s1; d = d1; break;
    case 2: s = s2; d = d2; break;
    default: s = s3; d = d3; break;
  }
  int i = blockIdx.x * blockDim.x + threadIdx.x;
  int stride = gridDim.x * blockDim.x;
  for (; i < n4; i += stride) {
    float4 v = ((const float4*)s)[i];
    u16x4 o = {f2bf(v.x), f2bf(v.y), f2bf(v.z), f2bf(v.w)};
    ((u16x4*)d)[i] = o;
  }
}

// ---------------- GEMM: C[M,N] = A[M,K](bf16) @ Bw[N,K](bf16)^T, +bias, *scale -------
// m97 structure: 128x128 tile, BK=32, 4 waves in 2x2, each 4x4 frags of 16x16x32.
template <int OUTF32>
__global__ __launch_bounds__(256) void gemm_bt(const u16* __restrict__ A, const u16* __restrict__ Bw,
                                               const float* __restrict__ bias, void* __restrict__ Cout,
                                               float scale) {
  __shared__ u16 As[128 * 32];
  __shared__ u16 Bs[128 * 32];
  const int K = D_MODEL, N = D_MODEL;
  int tid = threadIdx.x;
  int w = tid >> 6, lane = tid & 63, lg = lane >> 4, lr = lane & 15;
  int m0 = blockIdx.x * 128, n0 = blockIdx.y * 128;
  int wr = w >> 1, wc = w & 1;
  f32x4 acc[4][4] = {};
  int r0 = tid >> 2;           // rows 0..63  (staging instr 0)
  int r1 = 64 + (tid >> 2);    // rows 64..127 (staging instr 1)
  int kk0 = (tid & 3) * 8;
  for (int kb = 0; kb < K; kb += 32) {
    gload_lds16(A + (size_t)(m0 + r0) * K + kb + kk0, As + w * 512);
    gload_lds16(A + (size_t)(m0 + r1) * K + kb + kk0, As + 2048 + w * 512);
    gload_lds16(Bw + (size_t)(n0 + r0) * K + kb + kk0, Bs + w * 512);
    gload_lds16(Bw + (size_t)(n0 + r1) * K + kb + kk0, Bs + 2048 + w * 512);
    __syncthreads();
    bf16x8 af[4], bfr[4];
#pragma unroll
    for (int i = 0; i < 4; i++)
      af[i] = *(const bf16x8*)(As + (wr * 64 + i * 16 + lr) * 32 + lg * 8);
#pragma unroll
    for (int i = 0; i < 4; i++)
      bfr[i] = *(const bf16x8*)(Bs + (wc * 64 + i * 16 + lr) * 32 + lg * 8);
#pragma unroll
    for (int mi = 0; mi < 4; mi++)
#pragma unroll
      for (int ni = 0; ni < 4; ni++)
        acc[mi][ni] = MFMA16(af[mi], bfr[ni], acc[mi][ni]);
    __syncthreads();
  }
#pragma unroll
  for (int mi = 0; mi < 4; mi++)
#pragma unroll
    for (int ni = 0; ni < 4; ni++) {
      int col = n0 + wc * 64 + ni * 16 + lr;
      float bv = bias[col];
#pragma unroll
      for (int r = 0; r < 4; r++) {
        int row = m0 + wr * 64 + mi * 16 + lg * 4 + r;
        float v = (acc[mi][ni][r] + bv) * scale;
        if (OUTF32)
          ((float*)Cout)[(size_t)row * N + col] = v;
        else
          ((u16*)Cout)[(size_t)row * N + col] = f2bf(v);
      }
    }
}

// ---------------- fused attention: two-pass flash + attn materialization ------------
// grid (S/64, H, B), 256 threads = 4 waves; wave w owns q-rows [64*qb + 16w, +16).
__global__ __launch_bounds__(256) void attn_kernel(const u16* __restrict__ Qup, const u16* __restrict__ Kup,
                                                   const u16* __restrict__ Vup, const int* __restrict__ mask,
                                                   float* __restrict__ attn_out, u16* __restrict__ ctx) {
  __shared__ u16 p_lds[64][72];  // P tile (bf16), +8 pad -> 2-way (free) bank alias
  __shared__ u16 vt[64][72];     // V^T tile: vt[dh][sk]
  int tid = threadIdx.x;
  int w = tid >> 6, lane = tid & 63, lg = lane >> 4, lr = lane & 15;
  int q0 = blockIdx.x * 64, h = blockIdx.y, b = blockIdx.z;
  int band = w * 16;
  const float L2E = 1.4426950408889634f;
  const float NEGV = -100000000.0f;

  bf16x8 qf[2];
  {
    const u16* qrow = Qup + (size_t)(b * S_LEN + q0 + band + lr) * D_MODEL + h * D_HEAD;
    qf[0] = *(const bf16x8*)(qrow + lg * 8);
    qf[1] = *(const bf16x8*)(qrow + 32 + lg * 8);
  }
  const u16* Kb = Kup + (size_t)(b * S_LEN) * D_MODEL + h * D_HEAD;
  const u16* Vb = Vup + (size_t)(b * S_LEN) * D_MODEL + h * D_HEAD;
  const int* mb = mask + (size_t)b * S_LEN * S_LEN;
  float* attn_b = attn_out + (size_t)(b * N_HEAD + h) * S_LEN * S_LEN;

  float mrow[4] = {-3.0e38f, -3.0e38f, -3.0e38f, -3.0e38f};
  float lsum[4] = {0.f, 0.f, 0.f, 0.f};
  float inv_l[4];
  f32x4 ctxacc[4] = {};

  for (int pass = 0; pass < 2; pass++) {
    if (pass == 1) {
#pragma unroll
      for (int r = 0; r < 4; r++) inv_l[r] = 1.0f / lsum[r];
    }
    for (int kb = 0; kb < S_LEN; kb += 64) {
      if (pass == 1) {
        // cooperative stage of V^T (contraction index sk is strided in global)
#pragma unroll
        for (int c = 0; c < 2; c++) {
          int kk = c * 32 + (tid >> 3);
          int d0 = (tid & 7) * 8;
          bf16x8 v = *(const bf16x8*)(Vb + (size_t)(kb + kk) * D_MODEL + d0);
#pragma unroll
          for (int j = 0; j < 8; j++) vt[d0 + j][kk] = (u16)v[j];
        }
      }
      // scores: 16q x 64k per wave; K-frags straight from global (dh contiguous, L2-hot)
      f32x4 sc[4];
#pragma unroll
      for (int t = 0; t < 4; t++) {
        const u16* krow = Kb + (size_t)(kb + t * 16 + lr) * D_MODEL;
        bf16x8 k0 = *(const bf16x8*)(krow + lg * 8);
        bf16x8 k1 = *(const bf16x8*)(krow + 32 + lg * 8);
        f32x4 a = {0.f, 0.f, 0.f, 0.f};
        a = MFMA16(qf[0], k0, a);
        a = MFMA16(qf[1], k1, a);
        sc[t] = a;
      }
      // mask: True -> NEG (reference: where(mask, NEG, scores))
#pragma unroll
      for (int r = 0; r < 4; r++) {
        int sq = q0 + band + lg * 4 + r;
        const int* mr = mb + (size_t)sq * S_LEN + kb + lr;
#pragma unroll
        for (int t = 0; t < 4; t++)
          if (mr[t * 16] != 0) sc[t][r] = NEGV;
      }
      if (pass == 0) {
        // online max/sum; row lives in 16 lanes sharing lg, 4 tiles
#pragma unroll
        for (int r = 0; r < 4; r++) {
          float mx = fmaxf(fmaxf(sc[0][r], sc[1][r]), fmaxf(sc[2][r], sc[3][r]));
          for (int o = 1; o < 16; o <<= 1) mx = fmaxf(mx, __shfl_xor(mx, o));
          float mn = fmaxf(mrow[r], mx);
          float corr = exp2f((mrow[r] - mn) * L2E);
          float s = 0.f;
#pragma unroll
          for (int t = 0; t < 4; t++) s += exp2f((sc[t][r] - mn) * L2E);
          for (int o = 1; o < 16; o <<= 1) s += __shfl_xor(s, o);
          lsum[r] = lsum[r] * corr + s;
          mrow[r] = mn;
        }
      } else {
        // normalize, write attn (fp32), stage P (bf16) for PV
#pragma unroll
        for (int r = 0; r < 4; r++) {
          int sql = band + lg * 4 + r;
          float* arow = attn_b + (size_t)(q0 + sql) * S_LEN + kb + lr;
#pragma unroll
          for (int t = 0; t < 4; t++) {
            float p = exp2f((sc[t][r] - mrow[r]) * L2E) * inv_l[r];
            arow[t * 16] = p;
            p_lds[sql][t * 16 + lr] = f2bf(p);
          }
        }
        __syncthreads();
        bf16x8 pa0 = *(const bf16x8*)(&p_lds[band + lr][lg * 8]);
        bf16x8 pa1 = *(const bf16x8*)(&p_lds[band + lr][32 + lg * 8]);
#pragma unroll
        for (int t = 0; t < 4; t++) {
          bf16x8 v0 = *(const bf16x8*)(&vt[t * 16 + lr][lg * 8]);
          bf16x8 v1 = *(const bf16x8*)(&vt[t * 16 + lr][32 + lg * 8]);
          ctxacc[t] = MFMA16(pa0, v0, ctxacc[t]);
          ctxacc[t] = MFMA16(pa1, v1, ctxacc[t]);
        }
        __syncthreads();
      }
    }
  }
  // context out, [B,S,H,DH] == [M_TOK, D] row-major (matches transpose+reshape)
#pragma unroll
  for (int t = 0; t < 4; t++)
#pragma unroll
    for (int r = 0; r < 4; r++) {
      int sq = q0 + band + lg * 4 + r;
      ctx[(size_t)(b * S_LEN + sq) * D_MODEL + h * D_HEAD + t * 16 + lr] = f2bf(ctxacc[t][r]);
    }
}

// ---------------- workspace layout (u16 units) ----------------
#define O_KBF 0u
#define O_VBF 4194304u
#define O_QBF 8388608u
#define O_WQ 12582912u
#define O_WK 13631488u
#define O_WV 14680064u
#define O_WO 15728640u
#define O_QUP 16777216u
#define O_KUP 20971520u
#define O_VUP 25165824u
#define O_CTX 29360128u
// total = 33554432 u16 = 64 MiB

extern "C" void kernel_launch(void* const* d_in, const int* in_sizes, int n_in,
                              void* d_out, int out_size, void* d_ws, size_t ws_size,
                              hipStream_t stream) {
  const float* key = (const float*)d_in[0];
  const float* value = (const float*)d_in[1];
  const float* query = (const float*)d_in[2];
  const int* mask = (const int*)d_in[3];
  const float* Wq = (const float*)d_in[4];
  const float* bq = (const float*)d_in[5];
  const float* Wk = (const float*)d_in[6];
  const float* bk = (const float*)d_in[7];
  const float* Wv = (const float*)d_in[8];
  const float* bv = (const float*)d_in[9];
  const float* Wo = (const float*)d_in[10];
  const float* bo = (const float*)d_in[11];

  u16* ws = (u16*)d_ws;
  u16* kbf = ws + O_KBF;
  u16* vbf = ws + O_VBF;
  u16* qbf = ws + O_QBF;
  u16* wqb = ws + O_WQ;
  u16* wkb = ws + O_WK;
  u16* wvb = ws + O_WV;
  u16* wob = ws + O_WO;
  u16* qup = ws + O_QUP;
  u16* kup = ws + O_KUP;
  u16* vup = ws + O_VUP;
  u16* ctxb = ws + O_CTX;

  float* out = (float*)d_out;
  float* attn = out + (size_t)N_BATCH * S_LEN * D_MODEL;

  // fp32 -> bf16 converts
  cvt_kernel<<<dim3(1024, 3), 256, 0, stream>>>(key, value, query, key, kbf, vbf, qbf, kbf,
                                                M_TOK * D_MODEL / 4);
  cvt_kernel<<<dim3(512, 4), 256, 0, stream>>>(Wq, Wk, Wv, Wo, wqb, wkb, wvb, wob,
                                               D_MODEL * D_MODEL / 4);
  // projections (Q scaled by 1/sqrt(DH) after bias, matching reference)
  gemm_bt<0><<<dim3(32, 8), 256, 0, stream>>>(kbf, wkb, bk, kup, 1.0f);
  gemm_bt<0><<<dim3(32, 8), 256, 0, stream>>>(vbf, wvb, bv, vup, 1.0f);
  gemm_bt<0><<<dim3(32, 8), 256, 0, stream>>>(qbf, wqb, bq, qup, 0.125f);
  // attention
  attn_kernel<<<dim3(S_LEN / 64, N_HEAD, N_BATCH), 256, 0, stream>>>(qup, kup, vup, mask, attn, ctxb);
  // output projection (fp32 out)
  gemm_bt<1><<<dim3(32, 8), 256, 0, stream>>>(ctxb, wob, bo, out, 1.0f);
}